// Round 4
// baseline (129.219 us; speedup 1.0000x reference)
//
#include <hip/hip_runtime.h>
#include <hip/hip_bf16.h>

// Problem constants (AttentionalPlanarRemapping): N=32, C=64, H=W=128, E=512
#define NB   32
#define CC   64
#define HW   16384          // 128*128
#define EE   512
#define CC2  4096           // C*C

// ---------------------------------------------------------------------------
// Kernel 1: logits[n][j] = dot(atts[n,:], W[j,:]) + b[j]
// 1024 blocks x 256 threads. Block covers 4 j's x 32 n x 2 k-halves.
// Each thread does a 256-long half-dot; halves combined via LDS.
// W (8 MiB) is read exactly once across the grid.
// ---------------------------------------------------------------------------
__global__ __launch_bounds__(256) void logits_kernel(
    const float* __restrict__ atts, const float* __restrict__ W,
    const float* __restrict__ b, float* __restrict__ logits) {
    const int t  = threadIdx.x;
    const int j  = blockIdx.x * 4 + (t & 3);
    const int n  = (t >> 2) & 31;
    const int kh = t >> 7;                 // 0 or 1
    const float* __restrict__ wrow = W + (size_t)j * EE + kh * 256;
    const float* __restrict__ arow = atts + (size_t)n * EE + kh * 256;
    float acc0 = 0.f, acc1 = 0.f;
    #pragma unroll 4
    for (int k = 0; k < 256; k += 8) {
        float4 w0 = *reinterpret_cast<const float4*>(wrow + k);
        float4 a0 = *reinterpret_cast<const float4*>(arow + k);
        float4 w1 = *reinterpret_cast<const float4*>(wrow + k + 4);
        float4 a1 = *reinterpret_cast<const float4*>(arow + k + 4);
        acc0 = fmaf(w0.x, a0.x, acc0); acc0 = fmaf(w0.y, a0.y, acc0);
        acc0 = fmaf(w0.z, a0.z, acc0); acc0 = fmaf(w0.w, a0.w, acc0);
        acc1 = fmaf(w1.x, a1.x, acc1); acc1 = fmaf(w1.y, a1.y, acc1);
        acc1 = fmaf(w1.z, a1.z, acc1); acc1 = fmaf(w1.w, a1.w, acc1);
    }
    __shared__ float part[256];
    part[t] = acc0 + acc1;
    __syncthreads();
    if (t < 128) {
        logits[(size_t)n * CC2 + j] = part[t] + part[t + 128] + b[j];
    }
}

// ---------------------------------------------------------------------------
// Kernel 2: first softmax over the flattened 4096, then per-row (64) softmax.
// One block per n. Second softmax uses all 256 threads: 4 threads per row,
// quad shuffle-reduce. Output stored TRANSPOSED: aT[n][d][c] = a[n][c][d].
// ---------------------------------------------------------------------------
__global__ __launch_bounds__(256) void softmax_kernel(
    const float* __restrict__ logits, float* __restrict__ aT) {
    const int n = blockIdx.x;
    const int t = threadIdx.x;
    __shared__ float s[CC2];
    __shared__ float wmax[4];
    __shared__ float wsum[4];

    const float* __restrict__ L = logits + (size_t)n * CC2;

    // load + thread-local max
    float lmax = -1e30f;
    for (int i = t; i < CC2; i += 256) {
        float v = L[i];
        s[i] = v;
        lmax = fmaxf(lmax, v);
    }
    #pragma unroll
    for (int off = 32; off > 0; off >>= 1) lmax = fmaxf(lmax, __shfl_xor(lmax, off));
    if ((t & 63) == 0) wmax[t >> 6] = lmax;
    __syncthreads();
    const float bmax = fmaxf(fmaxf(wmax[0], wmax[1]), fmaxf(wmax[2], wmax[3]));

    // exp + thread-local sum
    float lsum = 0.f;
    for (int i = t; i < CC2; i += 256) {
        float e = __expf(s[i] - bmax);
        s[i] = e;
        lsum += e;
    }
    #pragma unroll
    for (int off = 32; off > 0; off >>= 1) lsum += __shfl_xor(lsum, off);
    if ((t & 63) == 0) wsum[t >> 6] = lsum;
    __syncthreads();
    const float inv = 1.f / (wsum[0] + wsum[1] + wsum[2] + wsum[3]);

    for (int i = t; i < CC2; i += 256) s[i] *= inv;
    __syncthreads();

    // second softmax: 4 threads per row c, each covering 16 d's
    const int c = t >> 2;          // 0..63
    const int q = t & 3;           // 0..3
    const float* __restrict__ row = s + c * CC + q * 16;
    float mx = -1e30f;
    #pragma unroll
    for (int i = 0; i < 16; ++i) mx = fmaxf(mx, row[i]);
    mx = fmaxf(mx, __shfl_xor(mx, 1));
    mx = fmaxf(mx, __shfl_xor(mx, 2));
    float sum = 0.f;
    #pragma unroll
    for (int i = 0; i < 16; ++i) sum += __expf(row[i] - mx);
    sum += __shfl_xor(sum, 1);
    sum += __shfl_xor(sum, 2);
    const float isum = 1.f / sum;
    float* __restrict__ dst = aT + (size_t)n * CC2 + c;   // aT[n][d][c]
    #pragma unroll
    for (int i = 0; i < 16; ++i) dst[(q * 16 + i) * CC] = __expf(row[i] - mx) * isum;
}

// ---------------------------------------------------------------------------
// Kernel 3: out[n,c,px] = sum_d a[n,c,d] * img[n,d,px]
// grid (32 px-tiles, 32 n) x 512 threads = 8 waves. WAVE = C-GROUP: wave w
// owns c = 8w..8w+7 and 512 px (8 px/lane: float4 at lane*4 and 256+lane*4,
// both perfectly coalesced, no intra-wave duplication -> 2 KB unique bytes
// per wave-load, 2 KB contiguous per (block,d)). acc[8][8]=64 VGPRs; depth-2
// prefetch keeps 4 loads in flight. __launch_bounds__(512,4) caps at 128
// VGPR so accs stay in arch VGPRs (no AGPR-move tax, no spill).
// Per d: 2 wave-uniform broadcast ds_read_b128 (a-values) + 64 FMA instrs.
// Image read once from HBM (8x c-group re-read is L1), out written once.
// ---------------------------------------------------------------------------
__global__ __launch_bounds__(512, 4) void einsum_kernel(
    const float* __restrict__ img, const float* __restrict__ aT,
    float* __restrict__ out) {
    const int n    = blockIdx.y;
    const int t    = threadIdx.x;
    const int wv   = t >> 6;                     // 0..7 wave = c-group
    const int lane = t & 63;
    const int c0   = wv * 8;
    const int pxA  = blockIdx.x * 512 + lane * 4;    // first float4
    // second float4 at pxA + 256

    __shared__ float4 sA[CC * CC / 4];           // sA[d*16 + c/4] = aT[n][d][c..c+3]
    {
        const float4* __restrict__ src = reinterpret_cast<const float4*>(aT + (size_t)n * CC2);
        sA[t]       = src[t];
        sA[t + 512] = src[t + 512];
    }
    __syncthreads();

    float acc[8][8];
    #pragma unroll
    for (int c = 0; c < 8; ++c)
        #pragma unroll
        for (int p = 0; p < 8; ++p) acc[c][p] = 0.f;

    const float* __restrict__ ip = img + (size_t)n * (CC * HW) + pxA;

    // depth-2 prefetch pipeline (clamped addresses, always in-bounds)
    float4 v0 = *reinterpret_cast<const float4*>(ip);
    float4 v1 = *reinterpret_cast<const float4*>(ip + 256);
    float4 u0 = *reinterpret_cast<const float4*>(ip + HW);
    float4 u1 = *reinterpret_cast<const float4*>(ip + HW + 256);

    #pragma unroll 4
    for (int d = 0; d < CC; ++d) {
        const int dn = (d + 2 < CC) ? d + 2 : CC - 1;
        float4 w0 = *reinterpret_cast<const float4*>(ip + (size_t)dn * HW);
        float4 w1 = *reinterpret_cast<const float4*>(ip + (size_t)dn * HW + 256);

        const float4 a0 = sA[d * 16 + wv * 2];
        const float4 a1 = sA[d * 16 + wv * 2 + 1];
        const float av[8] = {a0.x, a0.y, a0.z, a0.w, a1.x, a1.y, a1.z, a1.w};

        #pragma unroll
        for (int c = 0; c < 8; ++c) {
            acc[c][0] = fmaf(av[c], v0.x, acc[c][0]);
            acc[c][1] = fmaf(av[c], v0.y, acc[c][1]);
            acc[c][2] = fmaf(av[c], v0.z, acc[c][2]);
            acc[c][3] = fmaf(av[c], v0.w, acc[c][3]);
            acc[c][4] = fmaf(av[c], v1.x, acc[c][4]);
            acc[c][5] = fmaf(av[c], v1.y, acc[c][5]);
            acc[c][6] = fmaf(av[c], v1.z, acc[c][6]);
            acc[c][7] = fmaf(av[c], v1.w, acc[c][7]);
        }
        v0 = u0; v1 = u1;
        u0 = w0; u1 = w1;
    }

    float* __restrict__ op = out + (size_t)n * (CC * HW) + (size_t)c0 * HW + pxA;
    #pragma unroll
    for (int c = 0; c < 8; ++c) {
        float4 r0, r1;
        r0.x = acc[c][0]; r0.y = acc[c][1]; r0.z = acc[c][2]; r0.w = acc[c][3];
        r1.x = acc[c][4]; r1.y = acc[c][5]; r1.z = acc[c][6]; r1.w = acc[c][7];
        *reinterpret_cast<float4*>(op + (size_t)c * HW)       = r0;
        *reinterpret_cast<float4*>(op + (size_t)c * HW + 256) = r1;
    }
}

// ---------------------------------------------------------------------------
extern "C" void kernel_launch(void* const* d_in, const int* in_sizes, int n_in,
                              void* d_out, int out_size, void* d_ws, size_t ws_size,
                              hipStream_t stream) {
    const float* images = (const float*)d_in[0];   // [32,64,128,128]
    const float* atts   = (const float*)d_in[1];   // [32,512]
    const float* W      = (const float*)d_in[2];   // [4096,512]
    const float* b      = (const float*)d_in[3];   // [4096]
    float* out = (float*)d_out;                    // [32,64,128,128]

    // workspace: logits [32*4096] + aT [32*4096]  (1 MiB total)
    float* logits = (float*)d_ws;
    float* aT     = logits + NB * CC2;

    logits_kernel<<<CC2 / 4, 256, 0, stream>>>(atts, W, b, logits);
    softmax_kernel<<<NB, 256, 0, stream>>>(logits, aT);
    einsum_kernel<<<dim3(HW / 512, NB), 512, 0, stream>>>(images, aT, out);
}

// Round 5
// 106.028 us; speedup vs baseline: 1.2187x; 1.2187x over previous
//
#include <hip/hip_runtime.h>
#include <hip/hip_bf16.h>

// Problem constants (AttentionalPlanarRemapping): N=32, C=64, H=W=128, E=512
#define NB   32
#define CC   64
#define HW   16384          // 128*128
#define EE   512
#define CC2  4096           // C*C

using short8  = __attribute__((ext_vector_type(8))) short;
using f32x16  = __attribute__((ext_vector_type(16))) float;

// fp32 -> bf16 with round-to-nearest-even (bit twiddle, no API dependence)
__device__ __forceinline__ unsigned short f2bf(float x) {
    unsigned int u = __float_as_uint(x);
    u += 0x7FFFu + ((u >> 16) & 1u);
    return (unsigned short)(u >> 16);
}

// ---------------------------------------------------------------------------
// Kernel 1: logits[n][j] = dot(atts[n,:], W[j,:]) + b[j]   (unchanged)
// ---------------------------------------------------------------------------
__global__ __launch_bounds__(256) void logits_kernel(
    const float* __restrict__ atts, const float* __restrict__ W,
    const float* __restrict__ b, float* __restrict__ logits) {
    const int t  = threadIdx.x;
    const int j  = blockIdx.x * 4 + (t & 3);
    const int n  = (t >> 2) & 31;
    const int kh = t >> 7;                 // 0 or 1
    const float* __restrict__ wrow = W + (size_t)j * EE + kh * 256;
    const float* __restrict__ arow = atts + (size_t)n * EE + kh * 256;
    float acc0 = 0.f, acc1 = 0.f;
    #pragma unroll 4
    for (int k = 0; k < 256; k += 8) {
        float4 w0 = *reinterpret_cast<const float4*>(wrow + k);
        float4 a0 = *reinterpret_cast<const float4*>(arow + k);
        float4 w1 = *reinterpret_cast<const float4*>(wrow + k + 4);
        float4 a1 = *reinterpret_cast<const float4*>(arow + k + 4);
        acc0 = fmaf(w0.x, a0.x, acc0); acc0 = fmaf(w0.y, a0.y, acc0);
        acc0 = fmaf(w0.z, a0.z, acc0); acc0 = fmaf(w0.w, a0.w, acc0);
        acc1 = fmaf(w1.x, a1.x, acc1); acc1 = fmaf(w1.y, a1.y, acc1);
        acc1 = fmaf(w1.z, a1.z, acc1); acc1 = fmaf(w1.w, a1.w, acc1);
    }
    __shared__ float part[256];
    part[t] = acc0 + acc1;
    __syncthreads();
    if (t < 128) {
        logits[(size_t)n * CC2 + j] = part[t] + part[t + 128] + b[j];
    }
}

// ---------------------------------------------------------------------------
// Kernel 2: double softmax. One block per n. Output: a_bf[n][c][d] in BF16
// (natural row-major layout; rows are 128 B), RNE-converted.
// ---------------------------------------------------------------------------
__global__ __launch_bounds__(256) void softmax_kernel(
    const float* __restrict__ logits, unsigned short* __restrict__ a_bf) {
    const int n = blockIdx.x;
    const int t = threadIdx.x;
    __shared__ float s[CC2];
    __shared__ float wmax[4];
    __shared__ float wsum[4];

    const float* __restrict__ L = logits + (size_t)n * CC2;

    float lmax = -1e30f;
    for (int i = t; i < CC2; i += 256) {
        float v = L[i];
        s[i] = v;
        lmax = fmaxf(lmax, v);
    }
    #pragma unroll
    for (int off = 32; off > 0; off >>= 1) lmax = fmaxf(lmax, __shfl_xor(lmax, off));
    if ((t & 63) == 0) wmax[t >> 6] = lmax;
    __syncthreads();
    const float bmax = fmaxf(fmaxf(wmax[0], wmax[1]), fmaxf(wmax[2], wmax[3]));

    float lsum = 0.f;
    for (int i = t; i < CC2; i += 256) {
        float e = __expf(s[i] - bmax);
        s[i] = e;
        lsum += e;
    }
    #pragma unroll
    for (int off = 32; off > 0; off >>= 1) lsum += __shfl_xor(lsum, off);
    if ((t & 63) == 0) wsum[t >> 6] = lsum;
    __syncthreads();
    const float inv = 1.f / (wsum[0] + wsum[1] + wsum[2] + wsum[3]);

    for (int i = t; i < CC2; i += 256) s[i] *= inv;
    __syncthreads();

    // second softmax: 4 threads per row c, each covering 16 d's
    const int c = t >> 2;          // 0..63
    const int q = t & 3;           // 0..3
    const float* __restrict__ row = s + c * CC + q * 16;
    float mx = -1e30f;
    #pragma unroll
    for (int i = 0; i < 16; ++i) mx = fmaxf(mx, row[i]);
    mx = fmaxf(mx, __shfl_xor(mx, 1));
    mx = fmaxf(mx, __shfl_xor(mx, 2));
    float sum = 0.f;
    #pragma unroll
    for (int i = 0; i < 16; ++i) sum += __expf(row[i] - mx);
    sum += __shfl_xor(sum, 1);
    sum += __shfl_xor(sum, 2);
    const float isum = 1.f / sum;

    union { uint4 u[2]; unsigned short h[16]; } pk;
    #pragma unroll
    for (int i = 0; i < 16; ++i) pk.h[i] = f2bf(__expf(row[i] - mx) * isum);
    uint4* __restrict__ dst =
        reinterpret_cast<uint4*>(a_bf + (size_t)n * CC2 + c * CC + q * 16);
    dst[0] = pk.u[0];
    dst[1] = pk.u[1];
}

// ---------------------------------------------------------------------------
// Kernel 3 (MFMA): out[n,c,px] = sum_d a[n,c,d] * img[n,d,px]
// One wave per (n, 32-px column): D = A(64c x 64d, bf16) * B(64d x 32px, bf16)
// as 2 c-half tiles of v_mfma_f32_32x32x16_bf16, fp32 accumulate.
// No LDS, no barriers. B-frag: 8 strided dword loads (each instr = 2x128B
// dense) + RNE cvt. A-frag: 16 B contiguous from a_bf[n][c][d]. C/D layout:
// col=lane&31, row=(reg&3)+8*(reg>>2)+4*(lane>>5)  [verified m74/m101].
// A/B layout: row/col=lane%32, k=(lane/32)*8+e (canonical k-contiguous).
// ---------------------------------------------------------------------------
__global__ __launch_bounds__(512, 4) void einsum_kernel(
    const float* __restrict__ img, const unsigned short* __restrict__ a_bf,
    float* __restrict__ out) {
    const int t    = threadIdx.x;
    const int lane = t & 63;
    const int wid  = t >> 6;
    const int gw   = blockIdx.x * 8 + wid;     // 0..16383
    const int n    = gw >> 9;                  // 0..31
    const int px0  = (gw & 511) * 32;          // 0..16352
    const int lh   = lane >> 5;                // k-group half
    const int lc   = lane & 31;                // row (c) / col (px) within 32

    const float* __restrict__ ip =
        img + (size_t)n * (CC * HW) + px0 + lc;          // + d*HW
    const unsigned short* __restrict__ ap = a_bf + (size_t)n * CC2;

    f32x16 acc0 = {};   // c = 0..31
    f32x16 acc1 = {};   // c = 32..63

    #pragma unroll
    for (int ks = 0; ks < 4; ++ks) {
        const int kbase = ks * 16 + lh * 8;
        // B fragment: img[d = kbase..kbase+7][px0+lc], cvt to bf16
        float bv[8];
        #pragma unroll
        for (int e = 0; e < 8; ++e)
            bv[e] = ip[(size_t)(kbase + e) * HW];
        union { short8 v; unsigned short h[8]; } bf;
        #pragma unroll
        for (int e = 0; e < 8; ++e) bf.h[e] = f2bf(bv[e]);
        // A fragments: a_bf[c][kbase..kbase+7], 16 B each
        short8 a0 = *reinterpret_cast<const short8*>(ap + (size_t)lc * CC + kbase);
        short8 a1 = *reinterpret_cast<const short8*>(ap + (size_t)(lc + 32) * CC + kbase);
        acc0 = __builtin_amdgcn_mfma_f32_32x32x16_bf16(a0, bf.v, acc0, 0, 0, 0);
        acc1 = __builtin_amdgcn_mfma_f32_32x32x16_bf16(a1, bf.v, acc1, 0, 0, 0);
    }

    float* __restrict__ op = out + (size_t)n * (CC * HW) + px0 + lc;
    #pragma unroll
    for (int r = 0; r < 16; ++r) {
        const int row = (r & 3) + 8 * (r >> 2) + 4 * lh;
        op[(size_t)row * HW]        = acc0[r];
        op[(size_t)(row + 32) * HW] = acc1[r];
    }
}

// ---------------------------------------------------------------------------
extern "C" void kernel_launch(void* const* d_in, const int* in_sizes, int n_in,
                              void* d_out, int out_size, void* d_ws, size_t ws_size,
                              hipStream_t stream) {
    const float* images = (const float*)d_in[0];   // [32,64,128,128]
    const float* atts   = (const float*)d_in[1];   // [32,512]
    const float* W      = (const float*)d_in[2];   // [4096,512]
    const float* b      = (const float*)d_in[3];   // [4096]
    float* out = (float*)d_out;                    // [32,64,128,128]

    // workspace: logits f32 [32*4096] (512 KB) then a_bf bf16 [32*4096] (256 KB)
    float* logits = (float*)d_ws;
    unsigned short* a_bf = (unsigned short*)(logits + NB * CC2);

    logits_kernel<<<CC2 / 4, 256, 0, stream>>>(atts, W, b, logits);
    softmax_kernel<<<NB, 256, 0, stream>>>(logits, a_bf);
    einsum_kernel<<<2048, 512, 0, stream>>>(images, a_bf, out);
}

// Round 6
// 101.100 us; speedup vs baseline: 1.2781x; 1.0487x over previous
//
#include <hip/hip_runtime.h>
#include <hip/hip_bf16.h>

// Problem constants (AttentionalPlanarRemapping): N=32, C=64, H=W=128, E=512
#define NB   32
#define CC   64
#define HW   16384          // 128*128
#define EE   512
#define CC2  4096           // C*C

using short8  = __attribute__((ext_vector_type(8))) short;
using f32x16  = __attribute__((ext_vector_type(16))) float;

// fp32 -> bf16 with round-to-nearest-even (bit twiddle, no API dependence)
__device__ __forceinline__ unsigned short f2bf(float x) {
    unsigned int u = __float_as_uint(x);
    u += 0x7FFFu + ((u >> 16) & 1u);
    return (unsigned short)(u >> 16);
}

// ---------------------------------------------------------------------------
// Kernel 1: logits[n][j] = dot(atts[n,:], W[j,:]) + b[j]   (unchanged)
// ---------------------------------------------------------------------------
__global__ __launch_bounds__(256) void logits_kernel(
    const float* __restrict__ atts, const float* __restrict__ W,
    const float* __restrict__ b, float* __restrict__ logits) {
    const int t  = threadIdx.x;
    const int j  = blockIdx.x * 4 + (t & 3);
    const int n  = (t >> 2) & 31;
    const int kh = t >> 7;                 // 0 or 1
    const float* __restrict__ wrow = W + (size_t)j * EE + kh * 256;
    const float* __restrict__ arow = atts + (size_t)n * EE + kh * 256;
    float acc0 = 0.f, acc1 = 0.f;
    #pragma unroll 4
    for (int k = 0; k < 256; k += 8) {
        float4 w0 = *reinterpret_cast<const float4*>(wrow + k);
        float4 a0 = *reinterpret_cast<const float4*>(arow + k);
        float4 w1 = *reinterpret_cast<const float4*>(wrow + k + 4);
        float4 a1 = *reinterpret_cast<const float4*>(arow + k + 4);
        acc0 = fmaf(w0.x, a0.x, acc0); acc0 = fmaf(w0.y, a0.y, acc0);
        acc0 = fmaf(w0.z, a0.z, acc0); acc0 = fmaf(w0.w, a0.w, acc0);
        acc1 = fmaf(w1.x, a1.x, acc1); acc1 = fmaf(w1.y, a1.y, acc1);
        acc1 = fmaf(w1.z, a1.z, acc1); acc1 = fmaf(w1.w, a1.w, acc1);
    }
    __shared__ float part[256];
    part[t] = acc0 + acc1;
    __syncthreads();
    if (t < 128) {
        logits[(size_t)n * CC2 + j] = part[t] + part[t + 128] + b[j];
    }
}

// ---------------------------------------------------------------------------
// Kernel 2: double softmax. One block per n. Output: a_bf[n][c][d] in BF16
// (natural row-major layout; rows are 128 B), RNE-converted.  (unchanged)
// ---------------------------------------------------------------------------
__global__ __launch_bounds__(256) void softmax_kernel(
    const float* __restrict__ logits, unsigned short* __restrict__ a_bf) {
    const int n = blockIdx.x;
    const int t = threadIdx.x;
    __shared__ float s[CC2];
    __shared__ float wmax[4];
    __shared__ float wsum[4];

    const float* __restrict__ L = logits + (size_t)n * CC2;

    float lmax = -1e30f;
    for (int i = t; i < CC2; i += 256) {
        float v = L[i];
        s[i] = v;
        lmax = fmaxf(lmax, v);
    }
    #pragma unroll
    for (int off = 32; off > 0; off >>= 1) lmax = fmaxf(lmax, __shfl_xor(lmax, off));
    if ((t & 63) == 0) wmax[t >> 6] = lmax;
    __syncthreads();
    const float bmax = fmaxf(fmaxf(wmax[0], wmax[1]), fmaxf(wmax[2], wmax[3]));

    float lsum = 0.f;
    for (int i = t; i < CC2; i += 256) {
        float e = __expf(s[i] - bmax);
        s[i] = e;
        lsum += e;
    }
    #pragma unroll
    for (int off = 32; off > 0; off >>= 1) lsum += __shfl_xor(lsum, off);
    if ((t & 63) == 0) wsum[t >> 6] = lsum;
    __syncthreads();
    const float inv = 1.f / (wsum[0] + wsum[1] + wsum[2] + wsum[3]);

    for (int i = t; i < CC2; i += 256) s[i] *= inv;
    __syncthreads();

    // second softmax: 4 threads per row c, each covering 16 d's
    const int c = t >> 2;          // 0..63
    const int q = t & 3;           // 0..3
    const float* __restrict__ row = s + c * CC + q * 16;
    float mx = -1e30f;
    #pragma unroll
    for (int i = 0; i < 16; ++i) mx = fmaxf(mx, row[i]);
    mx = fmaxf(mx, __shfl_xor(mx, 1));
    mx = fmaxf(mx, __shfl_xor(mx, 2));
    float sum = 0.f;
    #pragma unroll
    for (int i = 0; i < 16; ++i) sum += __expf(row[i] - mx);
    sum += __shfl_xor(sum, 1);
    sum += __shfl_xor(sum, 2);
    const float isum = 1.f / sum;

    union { uint4 u[2]; unsigned short h[16]; } pk;
    #pragma unroll
    for (int i = 0; i < 16; ++i) pk.h[i] = f2bf(__expf(row[i] - mx) * isum);
    uint4* __restrict__ dst =
        reinterpret_cast<uint4*>(a_bf + (size_t)n * CC2 + c * CC + q * 16);
    dst[0] = pk.u[0];
    dst[1] = pk.u[1];
}

// ---------------------------------------------------------------------------
// Kernel 3 (MFMA + LDS-staged B): out[n,c,px] = sum_d a[n,c,d]*img[n,d,px]
// grid (64 px-tiles, 32 n) x 512 thr (8 waves). Tile = [64 d][256 px].
// Stage: coalesced float4 img loads (1 KB unique/wave-instr), cvt to bf16,
// ds_write_b64 into sImg[d][px] (32 KB -> 4 blocks/CU). Compute: wave w owns
// px column w*32+lc; B-frag = 8x ds_read_u16/k-step (lanes span 32 banks,
// upper half 2-way broadcast = free); A-frag 16 B from L2-hot a_bf; 2x
// v_mfma_f32_32x32x16_bf16. C/D: col=lane&31, row=(r&3)+8*(r>>2)+4*lh.
// ---------------------------------------------------------------------------
__global__ __launch_bounds__(512) void einsum_kernel(
    const float* __restrict__ img, const unsigned short* __restrict__ a_bf,
    float* __restrict__ out) {
    const int t    = threadIdx.x;
    const int lane = t & 63;
    const int wv   = t >> 6;                   // wave 0..7
    const int n    = blockIdx.y;
    const int px0  = blockIdx.x * 256;
    const int lh   = lane >> 5;                // k-group half
    const int lc   = lane & 31;

    __shared__ unsigned short sImg[CC * 256];  // [d][px] bf16, 32 KB

    // ---- stage: 8 float4 loads/thread, cvt, b64 write ----
    {
        const int px_l = (t & 63) * 4;         // 0..252
        const int d0   = (t >> 6) * 8;         // 0,8,..,56
        const float* __restrict__ gp = img + (size_t)n * (CC * HW) + px0 + px_l;
        #pragma unroll
        for (int i = 0; i < 8; ++i) {
            const int d = d0 + i;
            const float4 v = *reinterpret_cast<const float4*>(gp + (size_t)d * HW);
            union { uint2 u; unsigned short h[4]; } pk;
            pk.h[0] = f2bf(v.x); pk.h[1] = f2bf(v.y);
            pk.h[2] = f2bf(v.z); pk.h[3] = f2bf(v.w);
            *reinterpret_cast<uint2*>(&sImg[d * 256 + px_l]) = pk.u;
        }
    }
    __syncthreads();

    // ---- compute ----
    const int px_w = wv * 32 + lc;
    const unsigned short* __restrict__ ap = a_bf + (size_t)n * CC2;

    f32x16 acc0 = {};   // c = 0..31
    f32x16 acc1 = {};   // c = 32..63

    #pragma unroll
    for (int ks = 0; ks < 4; ++ks) {
        const int kbase = ks * 16 + lh * 8;
        union { short8 v; unsigned short h[8]; } bf;
        #pragma unroll
        for (int e = 0; e < 8; ++e)
            bf.h[e] = sImg[(kbase + e) * 256 + px_w];
        short8 a0 = *reinterpret_cast<const short8*>(ap + (size_t)lc * CC + kbase);
        short8 a1 = *reinterpret_cast<const short8*>(ap + (size_t)(lc + 32) * CC + kbase);
        acc0 = __builtin_amdgcn_mfma_f32_32x32x16_bf16(a0, bf.v, acc0, 0, 0, 0);
        acc1 = __builtin_amdgcn_mfma_f32_32x32x16_bf16(a1, bf.v, acc1, 0, 0, 0);
    }

    float* __restrict__ op = out + (size_t)n * (CC * HW) + px0 + px_w;
    #pragma unroll
    for (int r = 0; r < 16; ++r) {
        const int row = (r & 3) + 8 * (r >> 2) + 4 * lh;
        op[(size_t)row * HW]        = acc0[r];
        op[(size_t)(row + 32) * HW] = acc1[r];
    }
}

// ---------------------------------------------------------------------------
extern "C" void kernel_launch(void* const* d_in, const int* in_sizes, int n_in,
                              void* d_out, int out_size, void* d_ws, size_t ws_size,
                              hipStream_t stream) {
    const float* images = (const float*)d_in[0];   // [32,64,128,128]
    const float* atts   = (const float*)d_in[1];   // [32,512]
    const float* W      = (const float*)d_in[2];   // [4096,512]
    const float* b      = (const float*)d_in[3];   // [4096]
    float* out = (float*)d_out;                    // [32,64,128,128]

    // workspace: logits f32 [32*4096] (512 KB) then a_bf bf16 [32*4096] (256 KB)
    float* logits = (float*)d_ws;
    unsigned short* a_bf = (unsigned short*)(logits + NB * CC2);

    logits_kernel<<<CC2 / 4, 256, 0, stream>>>(atts, W, b, logits);
    softmax_kernel<<<NB, 256, 0, stream>>>(logits, a_bf);
    einsum_kernel<<<dim3(HW / 256, NB), 512, 0, stream>>>(images, a_bf, out);
}

// Round 7
// 84.215 us; speedup vs baseline: 1.5344x; 1.2005x over previous
//
#include <hip/hip_runtime.h>
#include <hip/hip_bf16.h>

// Problem constants (AttentionalPlanarRemapping): N=32, C=64, H=W=128, E=512
#define NB   32
#define CC   64
#define HW   16384          // 128*128
#define EE   512
#define CC2  4096           // C*C

using short8  = __attribute__((ext_vector_type(8))) short;
using f32x16  = __attribute__((ext_vector_type(16))) float;

// fp32 -> bf16 with round-to-nearest-even (bit twiddle, no API dependence)
__device__ __forceinline__ unsigned short f2bf(float x) {
    unsigned int u = __float_as_uint(x);
    u += 0x7FFFu + ((u >> 16) & 1u);
    return (unsigned short)(u >> 16);
}

// ---------------------------------------------------------------------------
// Kernel 1: logits[n][j] = dot(atts[n,:], W[j,:]) + b[j]
// 2048 blocks x 256 threads. Block = 2 j x 32 n x 4 k-quarters.
// Each thread does a 128-long quarter-dot (2 chains); LDS 4-way reduce.
// W (8 MiB) read exactly once across the grid.
// ---------------------------------------------------------------------------
__global__ __launch_bounds__(256) void logits_kernel(
    const float* __restrict__ atts, const float* __restrict__ W,
    const float* __restrict__ b, float* __restrict__ logits) {
    const int t  = threadIdx.x;
    const int j  = blockIdx.x * 2 + (t & 1);
    const int n  = (t >> 1) & 31;
    const int kq = t >> 6;                 // 0..3
    const float* __restrict__ wrow = W + (size_t)j * EE + kq * 128;
    const float* __restrict__ arow = atts + (size_t)n * EE + kq * 128;
    float acc0 = 0.f, acc1 = 0.f;
    #pragma unroll
    for (int k = 0; k < 128; k += 8) {
        float4 w0 = *reinterpret_cast<const float4*>(wrow + k);
        float4 a0 = *reinterpret_cast<const float4*>(arow + k);
        float4 w1 = *reinterpret_cast<const float4*>(wrow + k + 4);
        float4 a1 = *reinterpret_cast<const float4*>(arow + k + 4);
        acc0 = fmaf(w0.x, a0.x, acc0); acc0 = fmaf(w0.y, a0.y, acc0);
        acc0 = fmaf(w0.z, a0.z, acc0); acc0 = fmaf(w0.w, a0.w, acc0);
        acc1 = fmaf(w1.x, a1.x, acc1); acc1 = fmaf(w1.y, a1.y, acc1);
        acc1 = fmaf(w1.z, a1.z, acc1); acc1 = fmaf(w1.w, a1.w, acc1);
    }
    __shared__ float part[256];
    part[t] = acc0 + acc1;           // index = kq*64 + n*2 + j  (== t)
    __syncthreads();
    if (t < 64) {
        const int jj = blockIdx.x * 2 + (t & 1);
        const int nn = t >> 1;
        const float r = part[t] + part[t + 64] + part[t + 128] + part[t + 192];
        logits[(size_t)nn * CC2 + jj] = r + b[jj];
    }
}

// ---------------------------------------------------------------------------
// Kernel 2: double softmax. One block per n. Output: a packed directly in
// MFMA A-fragment order: a_pk[n][ks][half][lane][8] bf16, where
//   a_pk[n][ks][half][l][e] = a[n][c = 32*half + (l&31)][k = ks*16 + (l>>5)*8 + e]
// so the einsum's A-load is one contiguous 16 B per lane (1 KB/wave, coalesced).
// ---------------------------------------------------------------------------
__global__ __launch_bounds__(256) void softmax_kernel(
    const float* __restrict__ logits, unsigned short* __restrict__ a_pk) {
    const int n = blockIdx.x;
    const int t = threadIdx.x;
    __shared__ float s[CC2];
    __shared__ float wmax[4];
    __shared__ float wsum[4];

    const float* __restrict__ L = logits + (size_t)n * CC2;

    float lmax = -1e30f;
    for (int i = t; i < CC2; i += 256) {
        float v = L[i];
        s[i] = v;
        lmax = fmaxf(lmax, v);
    }
    #pragma unroll
    for (int off = 32; off > 0; off >>= 1) lmax = fmaxf(lmax, __shfl_xor(lmax, off));
    if ((t & 63) == 0) wmax[t >> 6] = lmax;
    __syncthreads();
    const float bmax = fmaxf(fmaxf(wmax[0], wmax[1]), fmaxf(wmax[2], wmax[3]));

    float lsum = 0.f;
    for (int i = t; i < CC2; i += 256) {
        float e = __expf(s[i] - bmax);
        s[i] = e;
        lsum += e;
    }
    #pragma unroll
    for (int off = 32; off > 0; off >>= 1) lsum += __shfl_xor(lsum, off);
    if ((t & 63) == 0) wsum[t >> 6] = lsum;
    __syncthreads();
    const float inv = 1.f / (wsum[0] + wsum[1] + wsum[2] + wsum[3]);

    for (int i = t; i < CC2; i += 256) s[i] *= inv;
    __syncthreads();

    // second softmax: 4 threads per row c, each covering 16 d's (= one ks)
    const int c = t >> 2;          // 0..63
    const int q = t & 3;           // ks = 0..3
    const float* __restrict__ row = s + c * CC + q * 16;
    float mx = -1e30f;
    #pragma unroll
    for (int i = 0; i < 16; ++i) mx = fmaxf(mx, row[i]);
    mx = fmaxf(mx, __shfl_xor(mx, 1));
    mx = fmaxf(mx, __shfl_xor(mx, 2));
    float sum = 0.f;
    #pragma unroll
    for (int i = 0; i < 16; ++i) sum += __expf(row[i] - mx);
    sum += __shfl_xor(sum, 1);
    sum += __shfl_xor(sum, 2);
    const float isum = 1.f / sum;

    union { uint4 u[2]; unsigned short h[16]; } pk;
    #pragma unroll
    for (int i = 0; i < 16; ++i) pk.h[i] = f2bf(__expf(row[i] - mx) * isum);

    // packed store: half = c>>5, within-half row lc2 = c&31
    const int half = c >> 5;
    const int lc2  = c & 31;
    unsigned short* __restrict__ base =
        a_pk + (size_t)n * CC2 + (size_t)(q * 2 + half) * 512;
    *reinterpret_cast<uint4*>(base + lc2 * 8)        = pk.u[0];  // lane lh=0: k=q*16..+7
    *reinterpret_cast<uint4*>(base + (32 + lc2) * 8) = pk.u[1];  // lane lh=1: k=q*16+8..+15
}

// ---------------------------------------------------------------------------
// Kernel 3 (MFMA + LDS-staged B + packed A): out[n,c,px]=sum_d a[c,d]*img[d,px]
// grid (64 px-tiles, 32 n) x 512 thr (8 waves). Tile = [64 d][256 px].
// __launch_bounds__(512,4): 128-VGPR cap -> stage keeps 8 float4 in flight,
// compute keeps A-loads + B-builds pipelined (R6 was VGPR=32, serialized).
// A: one coalesced 16 B/lane load per (ks,half) from a_pk (L2-hot).
// B: 8x ds_read_u16/k-step (2-way bank alias = free). 2x mfma_32x32x16_bf16.
// Stores: nontemporal (write-once data; keep img resident in L2/L3).
// ---------------------------------------------------------------------------
__global__ __launch_bounds__(512, 4) void einsum_kernel(
    const float* __restrict__ img, const unsigned short* __restrict__ a_pk,
    float* __restrict__ out) {
    const int t    = threadIdx.x;
    const int lane = t & 63;
    const int wv   = t >> 6;                   // wave 0..7
    const int n    = blockIdx.y;
    const int px0  = blockIdx.x * 256;
    const int lh   = lane >> 5;                // k-group half
    const int lc   = lane & 31;

    __shared__ unsigned short sImg[CC * 256];  // [d][px] bf16, 32 KB

    // ---- stage: 8 independent float4 loads, then cvt + b64 LDS writes ----
    {
        const int px_l = (t & 63) * 4;         // 0..252
        const int d0   = (t >> 6) * 8;         // 0,8,..,56
        const float* __restrict__ gp = img + (size_t)n * (CC * HW) + px0 + px_l;
        float4 v0 = *reinterpret_cast<const float4*>(gp + (size_t)(d0 + 0) * HW);
        float4 v1 = *reinterpret_cast<const float4*>(gp + (size_t)(d0 + 1) * HW);
        float4 v2 = *reinterpret_cast<const float4*>(gp + (size_t)(d0 + 2) * HW);
        float4 v3 = *reinterpret_cast<const float4*>(gp + (size_t)(d0 + 3) * HW);
        float4 v4 = *reinterpret_cast<const float4*>(gp + (size_t)(d0 + 4) * HW);
        float4 v5 = *reinterpret_cast<const float4*>(gp + (size_t)(d0 + 5) * HW);
        float4 v6 = *reinterpret_cast<const float4*>(gp + (size_t)(d0 + 6) * HW);
        float4 v7 = *reinterpret_cast<const float4*>(gp + (size_t)(d0 + 7) * HW);
        union { uint2 u; unsigned short h[4]; } pk;
        #define STG(i, vv) \
            pk.h[0] = f2bf(vv.x); pk.h[1] = f2bf(vv.y); \
            pk.h[2] = f2bf(vv.z); pk.h[3] = f2bf(vv.w); \
            *reinterpret_cast<uint2*>(&sImg[(d0 + i) * 256 + px_l]) = pk.u;
        STG(0, v0) STG(1, v1) STG(2, v2) STG(3, v3)
        STG(4, v4) STG(5, v5) STG(6, v6) STG(7, v7)
        #undef STG
    }
    __syncthreads();

    // ---- compute ----
    const int px_w = wv * 32 + lc;
    const unsigned short* __restrict__ apn = a_pk + (size_t)n * CC2;

    f32x16 acc0 = {};   // c = 0..31
    f32x16 acc1 = {};   // c = 32..63

    #pragma unroll
    for (int ks = 0; ks < 4; ++ks) {
        const int kbase = ks * 16 + lh * 8;
        union { short8 v; unsigned short h[8]; } bf;
        #pragma unroll
        for (int e = 0; e < 8; ++e)
            bf.h[e] = sImg[(kbase + e) * 256 + px_w];
        short8 a0 = *reinterpret_cast<const short8*>(apn + (ks * 2 + 0) * 512 + lane * 8);
        short8 a1 = *reinterpret_cast<const short8*>(apn + (ks * 2 + 1) * 512 + lane * 8);
        acc0 = __builtin_amdgcn_mfma_f32_32x32x16_bf16(a0, bf.v, acc0, 0, 0, 0);
        acc1 = __builtin_amdgcn_mfma_f32_32x32x16_bf16(a1, bf.v, acc1, 0, 0, 0);
    }

    float* __restrict__ op = out + (size_t)n * (CC * HW) + px0 + px_w;
    #pragma unroll
    for (int r = 0; r < 16; ++r) {
        const int row = (r & 3) + 8 * (r >> 2) + 4 * lh;
        __builtin_nontemporal_store(acc0[r], op + (size_t)row * HW);
        __builtin_nontemporal_store(acc1[r], op + (size_t)(row + 32) * HW);
    }
}

// ---------------------------------------------------------------------------
extern "C" void kernel_launch(void* const* d_in, const int* in_sizes, int n_in,
                              void* d_out, int out_size, void* d_ws, size_t ws_size,
                              hipStream_t stream) {
    const float* images = (const float*)d_in[0];   // [32,64,128,128]
    const float* atts   = (const float*)d_in[1];   // [32,512]
    const float* W      = (const float*)d_in[2];   // [4096,512]
    const float* b      = (const float*)d_in[3];   // [4096]
    float* out = (float*)d_out;                    // [32,64,128,128]

    // workspace: logits f32 [32*4096] (512 KB) then a_pk bf16 [32*4096] (256 KB)
    float* logits = (float*)d_ws;
    unsigned short* a_pk = (unsigned short*)(logits + NB * CC2);

    logits_kernel<<<CC2 / 2, 256, 0, stream>>>(atts, W, b, logits);
    softmax_kernel<<<NB, 256, 0, stream>>>(logits, a_pk);
    einsum_kernel<<<dim3(HW / 256, NB), 512, 0, stream>>>(images, a_pk, out);
}